// Round 8
// baseline (113.783 us; speedup 1.0000x reference)
//
#include <hip/hip_runtime.h>
#include <hip/hip_bf16.h>
#include <hip/hip_fp16.h>

#define NWAVE 16
#define LOG2CHUNK 13
#define CHUNK (1 << LOG2CHUNK)
#define HIST8_WORDS 10240   // 40 KB LDS = 40960 u8 bins (covers nlocal <= 40960)

constexpr float PI_OVER_CUT = 3.14159265358979323846f / 5.0f;

// ============ u8 per-chunk LDS histogram + local rank + fused block partials ============
// One WG per chunk (8K neighbors). All lanes active; bins u8-packed 4/word.
// lrank8[j] = rank of neighbor j within its (chunk, atom) group.
// After the copy-out, each WG reduces its bins per 1024-atom group and
// atomicAdds to partials[] (u32, deterministic).

__global__ __launch_bounds__(1024) void chunk_hist_rank8(
    const int* __restrict__ idx0, unsigned char* __restrict__ lrank8,
    unsigned char* __restrict__ hist8, unsigned* __restrict__ partials,
    int nneigh, int nlocalp, int nblkB)
{
    __shared__ unsigned lds[HIST8_WORDS];
    int c = blockIdx.x;
    int t = threadIdx.x;
    int lane = t & 63, wid = t >> 6;
    int words = nlocalp >> 2;

    for (int w = t; w < words; w += 1024) lds[w] = 0u;
    __syncthreads();

    int jbeg = c << LOG2CHUNK;
    int jend = jbeg + CHUNK; if (jend > nneigh) jend = nneigh;
    for (int j = jbeg + t; j < jend; j += 1024) {
        int a = idx0[j];
        unsigned word = (unsigned)a >> 2;
        unsigned shift = ((unsigned)a & 3u) << 3;
        unsigned old = atomicAdd(&lds[word], 1u << shift);
        lrank8[j] = (unsigned char)((old >> shift) & 0xffu);
    }
    __syncthreads();

    // coalesced copy-out of this chunk's bins
    unsigned* hrow = (unsigned*)(hist8 + (size_t)c * nlocalp);
    for (int w = t; w < words; w += 1024) hrow[w] = lds[w];

    // fused per-1024-atom-group sums (256 words per group)
    for (int grp = wid; grp < nblkB; grp += 16) {
        int base = grp << 8;
        int stop = base + 256; if (stop > words) stop = words;
        unsigned s = 0;
        for (int w = base + lane; w < stop; w += 64) {
            unsigned v = lds[w];
            s += (v & 0xffu) + ((v >> 8) & 0xffu) + ((v >> 16) & 0xffu) + (v >> 24);
        }
        #pragma unroll
        for (int o = 32; o >= 1; o >>= 1) s += __shfl_xor(s, o, 64);
        if (lane == 0 && s) atomicAdd(&partials[grp], s);
    }
}

// ============ offsets + u8 chunk-prefix (transposed) in one pass ============
// Every block re-scans the (<=64) block partials itself. chunkpre8 layout [c][a].

__global__ __launch_bounds__(1024) void scan_offsets_chunkpre(
    const unsigned char* __restrict__ hist8, const unsigned* __restrict__ partials,
    unsigned* __restrict__ offsets, unsigned char* __restrict__ chunkpre8,
    int nlocal, int nblk, int nc, int nlocalp)
{
    __shared__ unsigned wsum[16];
    __shared__ unsigned sOff;
    int t = threadIdx.x;
    int lane = t & 63, wid = t >> 6;
    int a = blockIdx.x * 1024 + t;

    if (wid == 0) {
        unsigned p = (lane < nblk) ? partials[lane] : 0u;
        unsigned incl = p;
        #pragma unroll
        for (int o = 1; o < 64; o <<= 1) {
            unsigned u = __shfl_up(incl, o, 64);
            if (lane >= o) incl += u;
        }
        if (lane == blockIdx.x) sOff = incl - p;
    }

    unsigned v = 0;
    if (a < nlocal) {
        for (int c = 0; c < nc; ++c) {
            chunkpre8[(size_t)c * nlocalp + a] = (unsigned char)v;
            v += hist8[(size_t)c * nlocalp + a];
        }
    }

    unsigned incl = v;
    #pragma unroll
    for (int o = 1; o < 64; o <<= 1) {
        unsigned u = __shfl_up(incl, o, 64);
        if (lane >= o) incl += u;
    }
    if (lane == 63) wsum[wid] = incl;
    __syncthreads();
    if (t < 16) {
        unsigned u = wsum[t];
        unsigned wincl = u;
        #pragma unroll
        for (int o = 1; o < 16; o <<= 1) {
            unsigned x = __shfl_up(wincl, o, 64);
            if (t >= o) wincl += x;
        }
        wsum[t] = wincl - u;
    }
    __syncthreads();
    if (a < nlocal) {
        unsigned o = sOff + wsum[wid] + (incl - v);
        offsets[a] = o;
        if (a == nlocal - 1) offsets[nlocal] = o + v;
    }
}

// ============ fused geometry + atomic-free record scatter ============
// srec[p] = {f16 dx | f16 dy, f16 dz | spec<<16, f32 dist, f32 fcut}

__global__ __launch_bounds__(256) void geom_scatter_direct(
    const float* __restrict__ cart, const int* __restrict__ idx0,
    const int* __restrict__ idx1, const int* __restrict__ nspec,
    const unsigned char* __restrict__ lrank8, const unsigned* __restrict__ offsets,
    const unsigned char* __restrict__ chunkpre8, uint4* __restrict__ srec,
    int nneigh, int nlocalp)
{
    int j = blockIdx.x * blockDim.x + threadIdx.x;
    if (j >= nneigh) return;
    int i0 = idx0[j], i1 = idx1[j], s = nspec[j];
    int c = j >> LOG2CHUNK;
    unsigned p = offsets[i0] + (unsigned)chunkpre8[(size_t)c * nlocalp + i0]
                             + (unsigned)lrank8[j];
    float ax = cart[3*i0], ay = cart[3*i0+1], az = cart[3*i0+2];
    float bx = cart[3*i1], by = cart[3*i1+1], bz = cart[3*i1+2];
    float dxv = ax - bx, dyv = ay - by, dzv = az - bz;
    float d2 = dxv*dxv + dyv*dyv + dzv*dzv;
    float rinv = rsqrtf(d2);
    float dist = d2 * rinv;
    float fc = fmaf(0.5f, __cosf(dist * PI_OVER_CUT), 0.5f);
    float fcut = fc * fc;
    unsigned hx = __half_as_ushort(__float2half_rn(dxv * rinv));
    unsigned hy = __half_as_ushort(__float2half_rn(dyv * rinv));
    unsigned hz = __half_as_ushort(__float2half_rn(dzv * rinv));
    uint4 r;
    r.x = hx | (hy << 16);
    r.y = hz | ((unsigned)s << 16);
    r.z = __float_as_uint(dist);
    r.w = __float_as_uint(fcut);
    srec[p] = r;
}

// ============ density: one wave per atom, pure streaming reads ============
// lane = g*16+k: group g handles record beg+n+g, channel k. 10 unique sums.

__global__ __launch_bounds__(256) void density_seq(
    const float* __restrict__ rs, const float* __restrict__ inta,
    const float* __restrict__ params, const unsigned* __restrict__ offsets,
    const uint4* __restrict__ srec, float* __restrict__ out,
    int nlocal, int nneigh)
{
    int t = threadIdx.x;
    int lane = t & 63;
    int k = lane & 15, g = lane >> 4;
    int a = blockIdx.x * 4 + (t >> 6);
    if (a >= nlocal) return;

    float rs0 = rs[k],        rs1 = rs[16 + k],     rs2 = rs[32 + k],     rs3 = rs[48 + k];
    float ia0 = inta[k],      ia1 = inta[16 + k],   ia2 = inta[32 + k],   ia3 = inta[48 + k];
    float pp0 = params[k],    pp1 = params[16 + k], pp2 = params[32 + k], pp3 = params[48 + k];

    int beg = (int)offsets[a], end = (int)offsets[a + 1];
    int lim = nneigh - 1;

    float aw = 0.f, axl = 0.f, ayl = 0.f, azl = 0.f;
    float axx = 0.f, ayy = 0.f, azz = 0.f, axy = 0.f, axz = 0.f, ayz = 0.f;

    int p0 = beg + g; if (p0 > lim) p0 = lim;
    uint4 rec0 = srec[p0];

    for (int n = beg; n < end; n += 4) {
        int p1 = n + 4 + g; if (p1 > lim) p1 = lim;
        uint4 rec1 = srec[p1];

        int s = (int)(rec0.y >> 16);
        bool c1 = (s & 1) != 0, c2 = (s & 2) != 0;
        float dist = __uint_as_float(rec0.z);
        float fcut = __uint_as_float(rec0.w);
        float rsel = c2 ? (c1 ? rs3 : rs2) : (c1 ? rs1 : rs0);
        float isel = c2 ? (c1 ? ia3 : ia2) : (c1 ? ia1 : ia0);
        float psel = c2 ? (c1 ? pp3 : pp2) : (c1 ? pp1 : pp0);
        float dd  = dist - rsel;
        float rad = __expf(-isel * dd * dd);
        float w   = rad * fcut * psel;
        w = (n + g < end) ? w : 0.f;

        float dx = __half2float(__ushort_as_half((unsigned short)(rec0.x & 0xffffu)));
        float dy = __half2float(__ushort_as_half((unsigned short)(rec0.x >> 16)));
        float dz = __half2float(__ushort_as_half((unsigned short)(rec0.y & 0xffffu)));

        float wx = w * dx, wy = w * dy, wz = w * dz;
        aw  += w;
        axl += wx;  ayl += wy;  azl += wz;
        axx = fmaf(wx, dx, axx);  axy = fmaf(wx, dy, axy);  axz = fmaf(wx, dz, axz);
        ayy = fmaf(wy, dy, ayy);  ayz = fmaf(wy, dz, ayz);  azz = fmaf(wz, dz, azz);

        rec0 = rec1;
    }

    #define RED2(x) x += __shfl_xor(x, 16, 64); x += __shfl_xor(x, 32, 64)
    RED2(aw); RED2(axl); RED2(ayl); RED2(azl);
    RED2(axx); RED2(ayy); RED2(azz); RED2(axy); RED2(axz); RED2(ayz);
    #undef RED2

    if (g == 0) {
        float l0 = aw * aw;
        float l1 = axl*axl + ayl*ayl + azl*azl;
        float l2 = axx*axx + ayy*ayy + azz*azz + 2.f*(axy*axy + axz*axz + ayz*ayz);
        out[a*48 + k]      = l0;
        out[a*48 + 16 + k] = l1;
        out[a*48 + 32 + k] = l2;
    }
}

// ============ fallback (R1/R4-proven path, minimal workspace) ============

__global__ void hist_kernel(const int* __restrict__ idx0, unsigned* __restrict__ counts, int nneigh) {
    int j = blockIdx.x * blockDim.x + threadIdx.x;
    if (j < nneigh) atomicAdd(&counts[idx0[j]], 1u);
}

__global__ void scan_kernel_1blk(const unsigned* __restrict__ counts, unsigned* __restrict__ offsets,
                                 unsigned* __restrict__ cursor, int nlocal) {
    __shared__ unsigned part[1024];
    int t = threadIdx.x;
    int ch = (nlocal + 1023) / 1024;
    int base = t * ch;
    unsigned s = 0;
    for (int i = 0; i < ch; ++i) { int id = base + i; if (id < nlocal) s += counts[id]; }
    part[t] = s;
    __syncthreads();
    for (int off = 1; off < 1024; off <<= 1) {
        unsigned v = (t >= off) ? part[t - off] : 0u;
        __syncthreads();
        part[t] += v;
        __syncthreads();
    }
    unsigned run = (t == 0) ? 0u : part[t - 1];
    for (int i = 0; i < ch; ++i) {
        int id = base + i;
        if (id < nlocal) { offsets[id] = run; cursor[id] = run; run += counts[id]; }
    }
    if (t == 1023) offsets[nlocal] = part[1023];
}

__global__ __launch_bounds__(256) void scatter_idx(const int* __restrict__ idx0,
                                                   unsigned* __restrict__ cursor,
                                                   unsigned* __restrict__ sorted, int nneigh) {
    int j = blockIdx.x * blockDim.x + threadIdx.x;
    if (j < nneigh) {
        unsigned p = atomicAdd(&cursor[idx0[j]], 1u);
        sorted[p] = (unsigned)j;
    }
}

__global__ __launch_bounds__(256) void density_kernel(
    const float* __restrict__ cart, const float* __restrict__ rs,
    const float* __restrict__ inta, const float* __restrict__ params,
    const int* __restrict__ idx1, const int* __restrict__ nspec,
    const unsigned* __restrict__ offsets, const unsigned* __restrict__ sorted,
    float* __restrict__ out, int nlocal)
{
    int lane = threadIdx.x & 63;
    int a = blockIdx.x * 4 + (threadIdx.x >> 6);
    if (a >= nlocal) return;
    int k = lane & 15;
    int g = lane >> 4;
    float c0x = cart[3*a], c0y = cart[3*a+1], c0z = cart[3*a+2];
    int a1, b1, a2, b2;
    switch (g) {
      case 0:  a1=0; b1=0; a2=1; b2=1; break;
      case 1:  a1=0; b1=1; a2=1; b2=2; break;
      case 2:  a1=0; b1=2; a2=2; b2=0; break;
      default: a1=1; b1=0; a2=2; b2=1; break;
    }
    float acc0 = 0.f, acc1 = 0.f, acc2 = 0.f, acc3 = 0.f;
    unsigned beg = offsets[a], end = offsets[a + 1];
    for (unsigned n = beg; n < end; ++n) {
        int j  = (int)sorted[n];
        int i1 = idx1[j];
        int s  = nspec[j];
        float dxv = c0x - cart[3*i1];
        float dyv = c0y - cart[3*i1+1];
        float dzv = c0z - cart[3*i1+2];
        float d2   = dxv*dxv + dyv*dyv + dzv*dzv;
        float rinv = rsqrtf(d2);
        float dist = d2 * rinv;
        float dx = dxv * rinv, dy = dyv * rinv, dz = dzv * rinv;
        float fc   = 0.5f * __cosf(dist * PI_OVER_CUT) + 0.5f;
        float fcut = fc * fc;
        float tt   = dist - rs[s*NWAVE + k];
        float rad  = __expf(-inta[s*NWAVE + k] * tt * tt) * params[s*NWAVE + k];
        float f1 = (g == 0) ? fcut : fcut * (g == 1 ? dx : (g == 2 ? dy : dz));
        acc0 = fmaf(f1, rad, acc0);
        float pa1 = (a1 == 0 ? dx : (a1 == 1 ? dy : dz));
        float pb1 = (b1 == 0 ? dx : (b1 == 1 ? dy : dz));
        acc1 = fmaf(fcut * pa1 * pb1, rad, acc1);
        float pa2 = (a2 == 0 ? dx : (a2 == 1 ? dy : dz));
        float pb2 = (b2 == 0 ? dx : (b2 == 1 ? dy : dz));
        acc2 = fmaf(fcut * pa2 * pb2, rad, acc2);
        if (g == 0) acc3 = fmaf(fcut * dz * dz, rad, acc3);
    }
    float l0, l1, l2;
    if (g == 0) { l0 = acc0*acc0; l1 = 0.f;        l2 = acc1*acc1 + acc2*acc2 + acc3*acc3; }
    else        { l0 = 0.f;       l1 = acc0*acc0;  l2 = acc1*acc1 + acc2*acc2; }
    l0 += __shfl_xor(l0, 16, 64); l1 += __shfl_xor(l1, 16, 64); l2 += __shfl_xor(l2, 16, 64);
    l0 += __shfl_xor(l0, 32, 64); l1 += __shfl_xor(l1, 32, 64); l2 += __shfl_xor(l2, 32, 64);
    if (g == 0) {
        out[a*48 + k]      = l0;
        out[a*48 + 16 + k] = l1;
        out[a*48 + 32 + k] = l2;
    }
}

// ======================= launch =======================

extern "C" void kernel_launch(void* const* d_in, const int* in_sizes, int n_in,
                              void* d_out, int out_size, void* d_ws, size_t ws_size,
                              hipStream_t stream) {
    const float* cart   = (const float*)d_in[0];
    const float* rs     = (const float*)d_in[1];
    const float* inta   = (const float*)d_in[2];
    const float* params = (const float*)d_in[3];
    const int* atom_index    = (const int*)d_in[4];
    const int* neigh_species = (const int*)d_in[6];
    int nlocal = in_sizes[5];
    int nneigh = in_sizes[6];
    const int* idx0 = atom_index;
    const int* idx1 = atom_index + nneigh;

    int tb = 256;
    int nblkN = (nneigh + tb - 1) / tb;
    int nc = (nneigh + CHUNK - 1) >> LOG2CHUNK;
    int nlocalp = (nlocal + 255) & ~255;            // u8 bins padded (word + group aligned)
    int nblkB = (nlocal + 1023) / 1024;             // 1024-atom scan blocks

    char* ws = (char*)d_ws;
    size_t off = 0;
    auto carve = [&](size_t bytes) -> char* {
        off = (off + 255) & ~(size_t)255;
        char* p = ws + off; off += bytes; return p;
    };
    unsigned* offsets        = (unsigned*)carve(((size_t)nlocal + 1) * 4);
    unsigned* partials       = (unsigned*)carve(256 * 4);
    uint4*    srec           = (uint4*)carve((size_t)nneigh * 16);
    unsigned char* lrank8    = (unsigned char*)carve((size_t)nneigh);
    unsigned char* hist8     = (unsigned char*)carve((size_t)nc * nlocalp);
    unsigned char* chunkpre8 = (unsigned char*)carve((size_t)nc * nlocalp);
    // fallback extras (only used on slow path)
    unsigned* counts         = (unsigned*)carve((size_t)nlocal * 4);
    unsigned* cursor         = (unsigned*)carve((size_t)nlocal * 4);
    size_t need = off;

    bool fast = (ws_size >= need) && (nblkB <= 64) &&
                (nlocalp <= 4 * HIST8_WORDS) && (nc <= 512);

    if (fast) {
        hipMemsetAsync(partials, 0, (size_t)nblkB * 4, stream);
        chunk_hist_rank8<<<nc, 1024, 0, stream>>>(idx0, lrank8, hist8, partials,
                                                  nneigh, nlocalp, nblkB);
        scan_offsets_chunkpre<<<nblkB, 1024, 0, stream>>>(hist8, partials, offsets,
                                                          chunkpre8, nlocal, nblkB, nc,
                                                          nlocalp);
        geom_scatter_direct<<<nblkN, tb, 0, stream>>>(cart, idx0, idx1, neigh_species,
                                                      lrank8, offsets, chunkpre8, srec,
                                                      nneigh, nlocalp);
        density_seq<<<(nlocal + 3) / 4, 256, 0, stream>>>(rs, inta, params, offsets, srec,
                                                          (float*)d_out, nlocal, nneigh);
    } else {
        unsigned* sorted = (unsigned*)srec;   // reuse region
        hipMemsetAsync(counts, 0, (size_t)nlocal * 4, stream);
        hist_kernel<<<nblkN, tb, 0, stream>>>(idx0, counts, nneigh);
        scan_kernel_1blk<<<1, 1024, 0, stream>>>(counts, offsets, cursor, nlocal);
        scatter_idx<<<nblkN, tb, 0, stream>>>(idx0, cursor, sorted, nneigh);
        density_kernel<<<(nlocal + 3) / 4, 256, 0, stream>>>(cart, rs, inta, params, idx1,
                                                             neigh_species, offsets, sorted,
                                                             (float*)d_out, nlocal);
    }
}

// Round 9
// 84.048 us; speedup vs baseline: 1.3538x; 1.3538x over previous
//
#include <hip/hip_runtime.h>
#include <hip/hip_bf16.h>

#define NWAVE 16
#define LOG2CHUNK 14
#define CHUNK (1 << LOG2CHUNK)
#define HIST_WORDS 10240   // static LDS: 40KB = 20480 u16 bins (covers nlocal<=40960)

constexpr float PI_OVER_CUT = 3.14159265358979323846f / 5.0f;

// ============ per-chunk LDS histogram + local rank (NO global atomics) ============
// WG bid: chunk c = bid>>1, parity = bid&1. Handles atoms with (a&1)==parity.
// bin = a>>1; u16-packed counts in LDS; lrank[j] = rank within (chunk, atom).

__global__ __launch_bounds__(1024) void chunk_hist_rank(
    const int* __restrict__ idx0, unsigned short* __restrict__ lrank,
    unsigned short* __restrict__ hist16, int nneigh, int halfp)
{
    __shared__ unsigned lds[HIST_WORDS];
    int c = blockIdx.x >> 1;
    int parity = blockIdx.x & 1;
    int t = threadIdx.x;

    int words = halfp >> 1;
    for (int w = t; w < words; w += 1024) lds[w] = 0u;
    __syncthreads();

    int jbeg = c << LOG2CHUNK;
    int jend = jbeg + CHUNK; if (jend > nneigh) jend = nneigh;
    for (int j = jbeg + t; j < jend; j += 1024) {
        int a = idx0[j];
        if ((a & 1) == parity) {
            int bin = a >> 1;
            int word = bin >> 1;
            int shift = (bin & 1) << 4;
            unsigned old = atomicAdd(&lds[word], 1u << shift);
            lrank[j] = (unsigned short)((old >> shift) & 0xffffu);
        }
    }
    __syncthreads();

    unsigned* hrow = (unsigned*)(hist16 + (size_t)blockIdx.x * halfp);
    for (int w = t; w < words; w += 1024) hrow[w] = lds[w];
}

// ============ stage A: per-1024-atom-block aggregate counts ============

__global__ __launch_bounds__(1024) void count_partial(
    const unsigned short* __restrict__ hist16, unsigned* __restrict__ partials,
    int nlocal, int nc, int halfp)
{
    __shared__ unsigned wsum[16];
    int t = threadIdx.x;
    int lane = t & 63, wid = t >> 6;
    int a = blockIdx.x * 1024 + t;
    unsigned v = 0;
    if (a < nlocal) {
        int parity = a & 1, bin = a >> 1;
        for (int c = 0; c < nc; ++c)
            v += hist16[(size_t)(c * 2 + parity) * halfp + bin];
    }
    #pragma unroll
    for (int o = 32; o >= 1; o >>= 1) v += __shfl_xor(v, o, 64);
    if (lane == 0) wsum[wid] = v;
    __syncthreads();
    if (t == 0) {
        unsigned s = 0;
        #pragma unroll
        for (int i = 0; i < 16; ++i) s += wsum[i];
        partials[blockIdx.x] = s;
    }
}

// ============ stage B: offsets + transposed chunk-prefix in one pass ============
// Every block re-scans all block partials (<=64 u32) itself -> no extra dispatch.
// chunkpreT layout [c][a] (padded nlocalp): coalesced writes, L2-hot reads.

__global__ __launch_bounds__(1024) void scan_offsets_chunkpre(
    const unsigned short* __restrict__ hist16, const unsigned* __restrict__ partials,
    unsigned* __restrict__ offsets, unsigned short* __restrict__ chunkpreT,
    int nlocal, int nblk, int nc, int halfp, int nlocalp)
{
    __shared__ unsigned wsum[16];
    __shared__ unsigned sOff;
    int t = threadIdx.x;
    int lane = t & 63, wid = t >> 6;
    int a = blockIdx.x * 1024 + t;

    // wave 0: exclusive scan of the (<=64) block partials -> this block's base
    if (wid == 0) {
        unsigned p = (lane < nblk) ? partials[lane] : 0u;
        unsigned incl = p;
        #pragma unroll
        for (int o = 1; o < 64; o <<= 1) {
            unsigned u = __shfl_up(incl, o, 64);
            if (lane >= o) incl += u;
        }
        if (lane == blockIdx.x) sOff = incl - p;
    }

    // per-atom chunk prefix (transposed write) + per-atom total v
    unsigned v = 0;
    if (a < nlocal) {
        int parity = a & 1, bin = a >> 1;
        for (int c = 0; c < nc; ++c) {
            chunkpreT[(size_t)c * nlocalp + a] = (unsigned short)v;
            v += hist16[(size_t)(c * 2 + parity) * halfp + bin];
        }
    }

    // block-wide exclusive scan of v
    unsigned incl = v;
    #pragma unroll
    for (int o = 1; o < 64; o <<= 1) {
        unsigned u = __shfl_up(incl, o, 64);
        if (lane >= o) incl += u;
    }
    if (lane == 63) wsum[wid] = incl;
    __syncthreads();
    if (t < 16) {
        unsigned u = wsum[t];
        unsigned wincl = u;
        #pragma unroll
        for (int o = 1; o < 16; o <<= 1) {
            unsigned x = __shfl_up(wincl, o, 64);
            if (t >= o) wincl += x;
        }
        wsum[t] = wincl - u;   // exclusive wave prefix
    }
    __syncthreads();
    if (a < nlocal) {
        unsigned o = sOff + wsum[wid] + (incl - v);
        offsets[a] = o;
        if (a == nlocal - 1) offsets[nlocal] = o + v;
    }
}

// ============ fused geometry + atomic-free record scatter ============
// srec[p] = {dx, dy, dz, dist with species in low 2 mantissa bits}
// srecF[p] = fcut  (precomputed so density's hot loop has no cos)

__global__ __launch_bounds__(256) void geom_scatter_direct(
    const float* __restrict__ cart, const int* __restrict__ idx0,
    const int* __restrict__ idx1, const int* __restrict__ nspec,
    const unsigned short* __restrict__ lrank, const unsigned* __restrict__ offsets,
    const unsigned short* __restrict__ chunkpreT, float4* __restrict__ srec,
    float* __restrict__ srecF, int nneigh, int nlocalp)
{
    int j = blockIdx.x * blockDim.x + threadIdx.x;
    if (j >= nneigh) return;
    int i0 = idx0[j], i1 = idx1[j], s = nspec[j];
    int c = j >> LOG2CHUNK;
    unsigned p = offsets[i0] + (unsigned)chunkpreT[(size_t)c * nlocalp + i0]
                             + (unsigned)lrank[j];
    float ax = cart[3*i0], ay = cart[3*i0+1], az = cart[3*i0+2];
    float bx = cart[3*i1], by = cart[3*i1+1], bz = cart[3*i1+2];
    float dxv = ax - bx, dyv = ay - by, dzv = az - bz;
    float d2 = dxv*dxv + dyv*dyv + dzv*dzv;
    float rinv = rsqrtf(d2);
    float dist = d2 * rinv;
    float fc = fmaf(0.5f, __cosf(dist * PI_OVER_CUT), 0.5f);
    unsigned db = (__float_as_uint(dist) & ~3u) | (unsigned)s;
    srec[p] = make_float4(dxv * rinv, dyv * rinv, dzv * rinv, __uint_as_float(db));
    srecF[p] = fc * fc;
}

// ============ density: one wave per atom, pure streaming reads ============
// lane = g*16+k: group g handles records base+g and base+4+g per iteration
// (8 neighbors / wave-iter, two independent loads in flight). 10 unique sums.

__global__ __launch_bounds__(256) void density_seq(
    const float* __restrict__ rs, const float* __restrict__ inta,
    const float* __restrict__ params, const unsigned* __restrict__ offsets,
    const float4* __restrict__ srec, const float* __restrict__ srecF,
    float* __restrict__ out, int nlocal, int nneigh)
{
    int t = threadIdx.x;
    int lane = t & 63;
    int k = lane & 15, g = lane >> 4;
    int a = blockIdx.x * 4 + (t >> 6);
    if (a >= nlocal) return;

    float rs0 = rs[k],        rs1 = rs[16 + k],     rs2 = rs[32 + k],     rs3 = rs[48 + k];
    float ia0 = inta[k],      ia1 = inta[16 + k],   ia2 = inta[32 + k],   ia3 = inta[48 + k];
    float pp0 = params[k],    pp1 = params[16 + k], pp2 = params[32 + k], pp3 = params[48 + k];

    int beg = (int)offsets[a], end = (int)offsets[a + 1];
    int lim = nneigh - 1;

    float aw = 0.f, axl = 0.f, ayl = 0.f, azl = 0.f;
    float axx = 0.f, ayy = 0.f, azz = 0.f, axy = 0.f, axz = 0.f, ayz = 0.f;

    for (int base = beg; base < end; base += 8) {
        int q0 = base + g;
        int q1 = base + 4 + g;
        int p0 = q0 > lim ? lim : q0;
        int p1 = q1 > lim ? lim : q1;
        float4 r0 = srec[p0];
        float4 r1 = srec[p1];
        float  f0 = srecF[p0];
        float  f1 = srecF[p1];

        {
            unsigned u = __float_as_uint(r0.w);
            float dist = __uint_as_float(u & ~3u);
            bool c1 = (u & 1u) != 0u, c2 = (u & 2u) != 0u;
            float rsel = c2 ? (c1 ? rs3 : rs2) : (c1 ? rs1 : rs0);
            float isel = c2 ? (c1 ? ia3 : ia2) : (c1 ? ia1 : ia0);
            float psel = c2 ? (c1 ? pp3 : pp2) : (c1 ? pp1 : pp0);
            float dd  = dist - rsel;
            float w   = __expf(-isel * dd * dd) * (f0 * psel);
            w = (q0 < end) ? w : 0.f;
            float dx = r0.x, dy = r0.y, dz = r0.z;
            float wx = w * dx, wy = w * dy, wz = w * dz;
            aw  += w;
            axl += wx;  ayl += wy;  azl += wz;
            axx = fmaf(wx, dx, axx);  axy = fmaf(wx, dy, axy);  axz = fmaf(wx, dz, axz);
            ayy = fmaf(wy, dy, ayy);  ayz = fmaf(wy, dz, ayz);  azz = fmaf(wz, dz, azz);
        }
        {
            unsigned u = __float_as_uint(r1.w);
            float dist = __uint_as_float(u & ~3u);
            bool c1 = (u & 1u) != 0u, c2 = (u & 2u) != 0u;
            float rsel = c2 ? (c1 ? rs3 : rs2) : (c1 ? rs1 : rs0);
            float isel = c2 ? (c1 ? ia3 : ia2) : (c1 ? ia1 : ia0);
            float psel = c2 ? (c1 ? pp3 : pp2) : (c1 ? pp1 : pp0);
            float dd  = dist - rsel;
            float w   = __expf(-isel * dd * dd) * (f1 * psel);
            w = (q1 < end) ? w : 0.f;
            float dx = r1.x, dy = r1.y, dz = r1.z;
            float wx = w * dx, wy = w * dy, wz = w * dz;
            aw  += w;
            axl += wx;  ayl += wy;  azl += wz;
            axx = fmaf(wx, dx, axx);  axy = fmaf(wx, dy, axy);  axz = fmaf(wx, dz, axz);
            ayy = fmaf(wy, dy, ayy);  ayz = fmaf(wy, dz, ayz);  azz = fmaf(wz, dz, azz);
        }
    }

    #define RED2(x) x += __shfl_xor(x, 16, 64); x += __shfl_xor(x, 32, 64)
    RED2(aw); RED2(axl); RED2(ayl); RED2(azl);
    RED2(axx); RED2(ayy); RED2(azz); RED2(axy); RED2(axz); RED2(ayz);
    #undef RED2

    if (g == 0) {
        float l0 = aw * aw;
        float l1 = axl*axl + ayl*ayl + azl*azl;
        float l2 = axx*axx + ayy*ayy + azz*azz + 2.f*(axy*axy + axz*axz + ayz*ayz);
        out[a*48 + k]      = l0;
        out[a*48 + 16 + k] = l1;
        out[a*48 + 32 + k] = l2;
    }
}

// ============ fallback (R1/R4-proven path, minimal workspace) ============

__global__ void hist_kernel(const int* __restrict__ idx0, unsigned* __restrict__ counts, int nneigh) {
    int j = blockIdx.x * blockDim.x + threadIdx.x;
    if (j < nneigh) atomicAdd(&counts[idx0[j]], 1u);
}

__global__ void scan_kernel_1blk(const unsigned* __restrict__ counts, unsigned* __restrict__ offsets,
                                 unsigned* __restrict__ cursor, int nlocal) {
    __shared__ unsigned part[1024];
    int t = threadIdx.x;
    int ch = (nlocal + 1023) / 1024;
    int base = t * ch;
    unsigned s = 0;
    for (int i = 0; i < ch; ++i) { int id = base + i; if (id < nlocal) s += counts[id]; }
    part[t] = s;
    __syncthreads();
    for (int off = 1; off < 1024; off <<= 1) {
        unsigned v = (t >= off) ? part[t - off] : 0u;
        __syncthreads();
        part[t] += v;
        __syncthreads();
    }
    unsigned run = (t == 0) ? 0u : part[t - 1];
    for (int i = 0; i < ch; ++i) {
        int id = base + i;
        if (id < nlocal) { offsets[id] = run; cursor[id] = run; run += counts[id]; }
    }
    if (t == 1023) offsets[nlocal] = part[1023];
}

__global__ __launch_bounds__(256) void scatter_idx(const int* __restrict__ idx0,
                                                   unsigned* __restrict__ cursor,
                                                   unsigned* __restrict__ sorted, int nneigh) {
    int j = blockIdx.x * blockDim.x + threadIdx.x;
    if (j < nneigh) {
        unsigned p = atomicAdd(&cursor[idx0[j]], 1u);
        sorted[p] = (unsigned)j;
    }
}

__global__ __launch_bounds__(256) void density_kernel(
    const float* __restrict__ cart, const float* __restrict__ rs,
    const float* __restrict__ inta, const float* __restrict__ params,
    const int* __restrict__ idx1, const int* __restrict__ nspec,
    const unsigned* __restrict__ offsets, const unsigned* __restrict__ sorted,
    float* __restrict__ out, int nlocal)
{
    int lane = threadIdx.x & 63;
    int a = blockIdx.x * 4 + (threadIdx.x >> 6);
    if (a >= nlocal) return;
    int k = lane & 15;
    int g = lane >> 4;
    float c0x = cart[3*a], c0y = cart[3*a+1], c0z = cart[3*a+2];
    int a1, b1, a2, b2;
    switch (g) {
      case 0:  a1=0; b1=0; a2=1; b2=1; break;
      case 1:  a1=0; b1=1; a2=1; b2=2; break;
      case 2:  a1=0; b1=2; a2=2; b2=0; break;
      default: a1=1; b1=0; a2=2; b2=1; break;
    }
    float acc0 = 0.f, acc1 = 0.f, acc2 = 0.f, acc3 = 0.f;
    unsigned beg = offsets[a], end = offsets[a + 1];
    for (unsigned n = beg; n < end; ++n) {
        int j  = (int)sorted[n];
        int i1 = idx1[j];
        int s  = nspec[j];
        float dxv = c0x - cart[3*i1];
        float dyv = c0y - cart[3*i1+1];
        float dzv = c0z - cart[3*i1+2];
        float d2   = dxv*dxv + dyv*dyv + dzv*dzv;
        float rinv = rsqrtf(d2);
        float dist = d2 * rinv;
        float dx = dxv * rinv, dy = dyv * rinv, dz = dzv * rinv;
        float fc   = 0.5f * __cosf(dist * PI_OVER_CUT) + 0.5f;
        float fcut = fc * fc;
        float tt   = dist - rs[s*NWAVE + k];
        float rad  = __expf(-inta[s*NWAVE + k] * tt * tt) * params[s*NWAVE + k];
        float f1 = (g == 0) ? fcut : fcut * (g == 1 ? dx : (g == 2 ? dy : dz));
        acc0 = fmaf(f1, rad, acc0);
        float pa1 = (a1 == 0 ? dx : (a1 == 1 ? dy : dz));
        float pb1 = (b1 == 0 ? dx : (b1 == 1 ? dy : dz));
        acc1 = fmaf(fcut * pa1 * pb1, rad, acc1);
        float pa2 = (a2 == 0 ? dx : (a2 == 1 ? dy : dz));
        float pb2 = (b2 == 0 ? dx : (b2 == 1 ? dy : dz));
        acc2 = fmaf(fcut * pa2 * pb2, rad, acc2);
        if (g == 0) acc3 = fmaf(fcut * dz * dz, rad, acc3);
    }
    float l0, l1, l2;
    if (g == 0) { l0 = acc0*acc0; l1 = 0.f;        l2 = acc1*acc1 + acc2*acc2 + acc3*acc3; }
    else        { l0 = 0.f;       l1 = acc0*acc0;  l2 = acc1*acc1 + acc2*acc2; }
    l0 += __shfl_xor(l0, 16, 64); l1 += __shfl_xor(l1, 16, 64); l2 += __shfl_xor(l2, 16, 64);
    l0 += __shfl_xor(l0, 32, 64); l1 += __shfl_xor(l1, 32, 64); l2 += __shfl_xor(l2, 32, 64);
    if (g == 0) {
        out[a*48 + k]      = l0;
        out[a*48 + 16 + k] = l1;
        out[a*48 + 32 + k] = l2;
    }
}

// ======================= launch =======================

extern "C" void kernel_launch(void* const* d_in, const int* in_sizes, int n_in,
                              void* d_out, int out_size, void* d_ws, size_t ws_size,
                              hipStream_t stream) {
    const float* cart   = (const float*)d_in[0];
    const float* rs     = (const float*)d_in[1];
    const float* inta   = (const float*)d_in[2];
    const float* params = (const float*)d_in[3];
    const int* atom_index    = (const int*)d_in[4];
    const int* neigh_species = (const int*)d_in[6];
    int nlocal = in_sizes[5];
    int nneigh = in_sizes[6];
    const int* idx0 = atom_index;
    const int* idx1 = atom_index + nneigh;

    int tb = 256;
    int nblkN = (nneigh + tb - 1) / tb;
    int nc = (nneigh + CHUNK - 1) >> LOG2CHUNK;
    int halfp = (((nlocal + 1) >> 1) + 63) & ~63;   // padded bins per parity
    int nlocalp = (nlocal + 63) & ~63;              // padded atoms (chunkpreT rows)
    int nblkB = (nlocal + 1023) / 1024;             // 1024-atom scan blocks

    char* ws = (char*)d_ws;
    size_t off = 0;
    auto carve = [&](size_t bytes) -> char* {
        off = (off + 255) & ~(size_t)255;
        char* p = ws + off; off += bytes; return p;
    };
    unsigned* counts        = (unsigned*)carve((size_t)nlocal * 4);
    unsigned* offsets       = (unsigned*)carve(((size_t)nlocal + 1) * 4);
    unsigned* cursor        = (unsigned*)carve((size_t)nlocal * 4);
    unsigned* partials      = (unsigned*)carve(256 * 4);
    float4*   srec          = (float4*)carve((size_t)nneigh * 16);
    float*    srecF         = (float*)carve((size_t)nneigh * 4);
    unsigned short* lrank   = (unsigned short*)carve((size_t)nneigh * 2);
    unsigned short* hist16  = (unsigned short*)carve((size_t)nc * 2 * halfp * 2);
    unsigned short* chunkpreT = (unsigned short*)carve((size_t)nc * nlocalp * 2);
    size_t need_fast = off;

    bool fast = (ws_size >= need_fast) && (nblkB <= 64) &&
                (halfp <= 2 * HIST_WORDS) && (nc <= 64);

    if (fast) {
        chunk_hist_rank<<<nc * 2, 1024, 0, stream>>>(idx0, lrank, hist16, nneigh, halfp);
        count_partial<<<nblkB, 1024, 0, stream>>>(hist16, partials, nlocal, nc, halfp);
        scan_offsets_chunkpre<<<nblkB, 1024, 0, stream>>>(hist16, partials, offsets,
                                                          chunkpreT, nlocal, nblkB, nc,
                                                          halfp, nlocalp);
        geom_scatter_direct<<<nblkN, tb, 0, stream>>>(cart, idx0, idx1, neigh_species,
                                                      lrank, offsets, chunkpreT, srec,
                                                      srecF, nneigh, nlocalp);
        density_seq<<<(nlocal + 3) / 4, 256, 0, stream>>>(rs, inta, params, offsets, srec,
                                                          srecF, (float*)d_out, nlocal, nneigh);
    } else {
        unsigned* sorted = (unsigned*)srec;   // reuse region
        hipMemsetAsync(counts, 0, (size_t)nlocal * 4, stream);
        hist_kernel<<<nblkN, tb, 0, stream>>>(idx0, counts, nneigh);
        scan_kernel_1blk<<<1, 1024, 0, stream>>>(counts, offsets, cursor, nlocal);
        scatter_idx<<<nblkN, tb, 0, stream>>>(idx0, cursor, sorted, nneigh);
        density_kernel<<<(nlocal + 3) / 4, 256, 0, stream>>>(cart, rs, inta, params, idx1,
                                                             neigh_species, offsets, sorted,
                                                             (float*)d_out, nlocal);
    }
}

// Round 10
// 77.790 us; speedup vs baseline: 1.4627x; 1.0804x over previous
//
#include <hip/hip_runtime.h>
#include <hip/hip_bf16.h>
#include <hip/hip_fp16.h>

#define NWAVE 16
#define LOG2CHUNK 14
#define CHUNK (1 << LOG2CHUNK)
#define HIST_WORDS 10240   // static LDS: 40KB = 20480 u16 bins (covers nlocal<=40960)

constexpr float PI_OVER_CUT = 3.14159265358979323846f / 5.0f;

// ============ per-chunk LDS histogram + local rank (NO global atomics) ============
// WG bid: chunk c = bid>>1, parity = bid&1. Handles atoms with (a&1)==parity.
// bin = a>>1; u16-packed counts in LDS; lrank[j] = rank within (chunk, atom).

__global__ __launch_bounds__(1024) void chunk_hist_rank(
    const int* __restrict__ idx0, unsigned short* __restrict__ lrank,
    unsigned short* __restrict__ hist16, int nneigh, int halfp)
{
    __shared__ unsigned lds[HIST_WORDS];
    int c = blockIdx.x >> 1;
    int parity = blockIdx.x & 1;
    int t = threadIdx.x;

    int words = halfp >> 1;
    for (int w = t; w < words; w += 1024) lds[w] = 0u;
    __syncthreads();

    int jbeg = c << LOG2CHUNK;
    int jend = jbeg + CHUNK; if (jend > nneigh) jend = nneigh;
    for (int j = jbeg + t; j < jend; j += 1024) {
        int a = idx0[j];
        if ((a & 1) == parity) {
            int bin = a >> 1;
            int word = bin >> 1;
            int shift = (bin & 1) << 4;
            unsigned old = atomicAdd(&lds[word], 1u << shift);
            lrank[j] = (unsigned short)((old >> shift) & 0xffffu);
        }
    }
    __syncthreads();

    unsigned* hrow = (unsigned*)(hist16 + (size_t)blockIdx.x * halfp);
    for (int w = t; w < words; w += 1024) hrow[w] = lds[w];
}

// ============ stage A: per-1024-atom-block aggregate counts ============

__global__ __launch_bounds__(1024) void count_partial(
    const unsigned short* __restrict__ hist16, unsigned* __restrict__ partials,
    int nlocal, int nc, int halfp)
{
    __shared__ unsigned wsum[16];
    int t = threadIdx.x;
    int lane = t & 63, wid = t >> 6;
    int a = blockIdx.x * 1024 + t;
    unsigned v = 0;
    if (a < nlocal) {
        int parity = a & 1, bin = a >> 1;
        for (int c = 0; c < nc; ++c)
            v += hist16[(size_t)(c * 2 + parity) * halfp + bin];
    }
    #pragma unroll
    for (int o = 32; o >= 1; o >>= 1) v += __shfl_xor(v, o, 64);
    if (lane == 0) wsum[wid] = v;
    __syncthreads();
    if (t == 0) {
        unsigned s = 0;
        #pragma unroll
        for (int i = 0; i < 16; ++i) s += wsum[i];
        partials[blockIdx.x] = s;
    }
}

// ============ stage B: offsets + transposed chunk-prefix in one pass ============

__global__ __launch_bounds__(1024) void scan_offsets_chunkpre(
    const unsigned short* __restrict__ hist16, const unsigned* __restrict__ partials,
    unsigned* __restrict__ offsets, unsigned short* __restrict__ chunkpreT,
    int nlocal, int nblk, int nc, int halfp, int nlocalp)
{
    __shared__ unsigned wsum[16];
    __shared__ unsigned sOff;
    int t = threadIdx.x;
    int lane = t & 63, wid = t >> 6;
    int a = blockIdx.x * 1024 + t;

    if (wid == 0) {
        unsigned p = (lane < nblk) ? partials[lane] : 0u;
        unsigned incl = p;
        #pragma unroll
        for (int o = 1; o < 64; o <<= 1) {
            unsigned u = __shfl_up(incl, o, 64);
            if (lane >= o) incl += u;
        }
        if (lane == blockIdx.x) sOff = incl - p;
    }

    unsigned v = 0;
    if (a < nlocal) {
        int parity = a & 1, bin = a >> 1;
        for (int c = 0; c < nc; ++c) {
            chunkpreT[(size_t)c * nlocalp + a] = (unsigned short)v;
            v += hist16[(size_t)(c * 2 + parity) * halfp + bin];
        }
    }

    unsigned incl = v;
    #pragma unroll
    for (int o = 1; o < 64; o <<= 1) {
        unsigned u = __shfl_up(incl, o, 64);
        if (lane >= o) incl += u;
    }
    if (lane == 63) wsum[wid] = incl;
    __syncthreads();
    if (t < 16) {
        unsigned u = wsum[t];
        unsigned wincl = u;
        #pragma unroll
        for (int o = 1; o < 16; o <<= 1) {
            unsigned x = __shfl_up(wincl, o, 64);
            if (t >= o) wincl += x;
        }
        wsum[t] = wincl - u;
    }
    __syncthreads();
    if (a < nlocal) {
        unsigned o = sOff + wsum[wid] + (incl - v);
        offsets[a] = o;
        if (a == nlocal - 1) offsets[nlocal] = o + v;
    }
}

// ============ fused geometry + atomic-free record scatter ============
// ONE 16B write per neighbor:
// srec[p] = {f16 dx | f16 dy<<16, f16 dz | spec<<16, f32 dist, f32 fcut}

__global__ __launch_bounds__(256) void geom_scatter_direct(
    const float* __restrict__ cart, const int* __restrict__ idx0,
    const int* __restrict__ idx1, const int* __restrict__ nspec,
    const unsigned short* __restrict__ lrank, const unsigned* __restrict__ offsets,
    const unsigned short* __restrict__ chunkpreT, uint4* __restrict__ srec,
    int nneigh, int nlocalp)
{
    int j = blockIdx.x * blockDim.x + threadIdx.x;
    if (j >= nneigh) return;
    int i0 = idx0[j], i1 = idx1[j], s = nspec[j];
    int c = j >> LOG2CHUNK;
    unsigned p = offsets[i0] + (unsigned)chunkpreT[(size_t)c * nlocalp + i0]
                             + (unsigned)lrank[j];
    float ax = cart[3*i0], ay = cart[3*i0+1], az = cart[3*i0+2];
    float bx = cart[3*i1], by = cart[3*i1+1], bz = cart[3*i1+2];
    float dxv = ax - bx, dyv = ay - by, dzv = az - bz;
    float d2 = dxv*dxv + dyv*dyv + dzv*dzv;
    float rinv = rsqrtf(d2);
    float dist = d2 * rinv;
    float fc = fmaf(0.5f, __cosf(dist * PI_OVER_CUT), 0.5f);
    unsigned hx = __half_as_ushort(__float2half_rn(dxv * rinv));
    unsigned hy = __half_as_ushort(__float2half_rn(dyv * rinv));
    unsigned hz = __half_as_ushort(__float2half_rn(dzv * rinv));
    uint4 r;
    r.x = hx | (hy << 16);
    r.y = hz | ((unsigned)s << 16);
    r.z = __float_as_uint(dist);
    r.w = __float_as_uint(fc * fc);
    srec[p] = r;
}

// ============ density: one wave per atom, streaming, 8 neighbors/iter ============
// lane = g*16+k: group g handles records base+g and base+4+g (two independent
// 16B loads in flight). 10 unique sums; no cos in the hot loop.

__global__ __launch_bounds__(256) void density_seq(
    const float* __restrict__ rs, const float* __restrict__ inta,
    const float* __restrict__ params, const unsigned* __restrict__ offsets,
    const uint4* __restrict__ srec, float* __restrict__ out,
    int nlocal, int nneigh)
{
    int t = threadIdx.x;
    int lane = t & 63;
    int k = lane & 15, g = lane >> 4;
    int a = blockIdx.x * 4 + (t >> 6);
    if (a >= nlocal) return;

    float rs0 = rs[k],        rs1 = rs[16 + k],     rs2 = rs[32 + k],     rs3 = rs[48 + k];
    float ia0 = inta[k],      ia1 = inta[16 + k],   ia2 = inta[32 + k],   ia3 = inta[48 + k];
    float pp0 = params[k],    pp1 = params[16 + k], pp2 = params[32 + k], pp3 = params[48 + k];

    int beg = (int)offsets[a], end = (int)offsets[a + 1];
    int lim = nneigh - 1;

    float aw = 0.f, axl = 0.f, ayl = 0.f, azl = 0.f;
    float axx = 0.f, ayy = 0.f, azz = 0.f, axy = 0.f, axz = 0.f, ayz = 0.f;

    for (int base = beg; base < end; base += 8) {
        int q0 = base + g;
        int q1 = base + 4 + g;
        int p0 = q0 > lim ? lim : q0;
        int p1 = q1 > lim ? lim : q1;
        uint4 r0 = srec[p0];
        uint4 r1 = srec[p1];

        {
            int s = (int)(r0.y >> 16);
            bool c1 = (s & 1) != 0, c2 = (s & 2) != 0;
            float dist = __uint_as_float(r0.z);
            float fcut = __uint_as_float(r0.w);
            float rsel = c2 ? (c1 ? rs3 : rs2) : (c1 ? rs1 : rs0);
            float isel = c2 ? (c1 ? ia3 : ia2) : (c1 ? ia1 : ia0);
            float psel = c2 ? (c1 ? pp3 : pp2) : (c1 ? pp1 : pp0);
            float dd  = dist - rsel;
            float w   = __expf(-isel * dd * dd) * (fcut * psel);
            w = (q0 < end) ? w : 0.f;
            float dx = __half2float(__ushort_as_half((unsigned short)(r0.x & 0xffffu)));
            float dy = __half2float(__ushort_as_half((unsigned short)(r0.x >> 16)));
            float dz = __half2float(__ushort_as_half((unsigned short)(r0.y & 0xffffu)));
            float wx = w * dx, wy = w * dy, wz = w * dz;
            aw  += w;
            axl += wx;  ayl += wy;  azl += wz;
            axx = fmaf(wx, dx, axx);  axy = fmaf(wx, dy, axy);  axz = fmaf(wx, dz, axz);
            ayy = fmaf(wy, dy, ayy);  ayz = fmaf(wy, dz, ayz);  azz = fmaf(wz, dz, azz);
        }
        {
            int s = (int)(r1.y >> 16);
            bool c1 = (s & 1) != 0, c2 = (s & 2) != 0;
            float dist = __uint_as_float(r1.z);
            float fcut = __uint_as_float(r1.w);
            float rsel = c2 ? (c1 ? rs3 : rs2) : (c1 ? rs1 : rs0);
            float isel = c2 ? (c1 ? ia3 : ia2) : (c1 ? ia1 : ia0);
            float psel = c2 ? (c1 ? pp3 : pp2) : (c1 ? pp1 : pp0);
            float dd  = dist - rsel;
            float w   = __expf(-isel * dd * dd) * (fcut * psel);
            w = (q1 < end) ? w : 0.f;
            float dx = __half2float(__ushort_as_half((unsigned short)(r1.x & 0xffffu)));
            float dy = __half2float(__ushort_as_half((unsigned short)(r1.x >> 16)));
            float dz = __half2float(__ushort_as_half((unsigned short)(r1.y & 0xffffu)));
            float wx = w * dx, wy = w * dy, wz = w * dz;
            aw  += w;
            axl += wx;  ayl += wy;  azl += wz;
            axx = fmaf(wx, dx, axx);  axy = fmaf(wx, dy, axy);  axz = fmaf(wx, dz, axz);
            ayy = fmaf(wy, dy, ayy);  ayz = fmaf(wy, dz, ayz);  azz = fmaf(wz, dz, azz);
        }
    }

    #define RED2(x) x += __shfl_xor(x, 16, 64); x += __shfl_xor(x, 32, 64)
    RED2(aw); RED2(axl); RED2(ayl); RED2(azl);
    RED2(axx); RED2(ayy); RED2(azz); RED2(axy); RED2(axz); RED2(ayz);
    #undef RED2

    if (g == 0) {
        float l0 = aw * aw;
        float l1 = axl*axl + ayl*ayl + azl*azl;
        float l2 = axx*axx + ayy*ayy + azz*azz + 2.f*(axy*axy + axz*axz + ayz*ayz);
        out[a*48 + k]      = l0;
        out[a*48 + 16 + k] = l1;
        out[a*48 + 32 + k] = l2;
    }
}

// ============ fallback (R1/R4-proven path, minimal workspace) ============

__global__ void hist_kernel(const int* __restrict__ idx0, unsigned* __restrict__ counts, int nneigh) {
    int j = blockIdx.x * blockDim.x + threadIdx.x;
    if (j < nneigh) atomicAdd(&counts[idx0[j]], 1u);
}

__global__ void scan_kernel_1blk(const unsigned* __restrict__ counts, unsigned* __restrict__ offsets,
                                 unsigned* __restrict__ cursor, int nlocal) {
    __shared__ unsigned part[1024];
    int t = threadIdx.x;
    int ch = (nlocal + 1023) / 1024;
    int base = t * ch;
    unsigned s = 0;
    for (int i = 0; i < ch; ++i) { int id = base + i; if (id < nlocal) s += counts[id]; }
    part[t] = s;
    __syncthreads();
    for (int off = 1; off < 1024; off <<= 1) {
        unsigned v = (t >= off) ? part[t - off] : 0u;
        __syncthreads();
        part[t] += v;
        __syncthreads();
    }
    unsigned run = (t == 0) ? 0u : part[t - 1];
    for (int i = 0; i < ch; ++i) {
        int id = base + i;
        if (id < nlocal) { offsets[id] = run; cursor[id] = run; run += counts[id]; }
    }
    if (t == 1023) offsets[nlocal] = part[1023];
}

__global__ __launch_bounds__(256) void scatter_idx(const int* __restrict__ idx0,
                                                   unsigned* __restrict__ cursor,
                                                   unsigned* __restrict__ sorted, int nneigh) {
    int j = blockIdx.x * blockDim.x + threadIdx.x;
    if (j < nneigh) {
        unsigned p = atomicAdd(&cursor[idx0[j]], 1u);
        sorted[p] = (unsigned)j;
    }
}

__global__ __launch_bounds__(256) void density_kernel(
    const float* __restrict__ cart, const float* __restrict__ rs,
    const float* __restrict__ inta, const float* __restrict__ params,
    const int* __restrict__ idx1, const int* __restrict__ nspec,
    const unsigned* __restrict__ offsets, const unsigned* __restrict__ sorted,
    float* __restrict__ out, int nlocal)
{
    int lane = threadIdx.x & 63;
    int a = blockIdx.x * 4 + (threadIdx.x >> 6);
    if (a >= nlocal) return;
    int k = lane & 15;
    int g = lane >> 4;
    float c0x = cart[3*a], c0y = cart[3*a+1], c0z = cart[3*a+2];
    int a1, b1, a2, b2;
    switch (g) {
      case 0:  a1=0; b1=0; a2=1; b2=1; break;
      case 1:  a1=0; b1=1; a2=1; b2=2; break;
      case 2:  a1=0; b1=2; a2=2; b2=0; break;
      default: a1=1; b1=0; a2=2; b2=1; break;
    }
    float acc0 = 0.f, acc1 = 0.f, acc2 = 0.f, acc3 = 0.f;
    unsigned beg = offsets[a], end = offsets[a + 1];
    for (unsigned n = beg; n < end; ++n) {
        int j  = (int)sorted[n];
        int i1 = idx1[j];
        int s  = nspec[j];
        float dxv = c0x - cart[3*i1];
        float dyv = c0y - cart[3*i1+1];
        float dzv = c0z - cart[3*i1+2];
        float d2   = dxv*dxv + dyv*dyv + dzv*dzv;
        float rinv = rsqrtf(d2);
        float dist = d2 * rinv;
        float dx = dxv * rinv, dy = dyv * rinv, dz = dzv * rinv;
        float fc   = 0.5f * __cosf(dist * PI_OVER_CUT) + 0.5f;
        float fcut = fc * fc;
        float tt   = dist - rs[s*NWAVE + k];
        float rad  = __expf(-inta[s*NWAVE + k] * tt * tt) * params[s*NWAVE + k];
        float f1 = (g == 0) ? fcut : fcut * (g == 1 ? dx : (g == 2 ? dy : dz));
        acc0 = fmaf(f1, rad, acc0);
        float pa1 = (a1 == 0 ? dx : (a1 == 1 ? dy : dz));
        float pb1 = (b1 == 0 ? dx : (b1 == 1 ? dy : dz));
        acc1 = fmaf(fcut * pa1 * pb1, rad, acc1);
        float pa2 = (a2 == 0 ? dx : (a2 == 1 ? dy : dz));
        float pb2 = (b2 == 0 ? dx : (b2 == 1 ? dy : dz));
        acc2 = fmaf(fcut * pa2 * pb2, rad, acc2);
        if (g == 0) acc3 = fmaf(fcut * dz * dz, rad, acc3);
    }
    float l0, l1, l2;
    if (g == 0) { l0 = acc0*acc0; l1 = 0.f;        l2 = acc1*acc1 + acc2*acc2 + acc3*acc3; }
    else        { l0 = 0.f;       l1 = acc0*acc0;  l2 = acc1*acc1 + acc2*acc2; }
    l0 += __shfl_xor(l0, 16, 64); l1 += __shfl_xor(l1, 16, 64); l2 += __shfl_xor(l2, 16, 64);
    l0 += __shfl_xor(l0, 32, 64); l1 += __shfl_xor(l1, 32, 64); l2 += __shfl_xor(l2, 32, 64);
    if (g == 0) {
        out[a*48 + k]      = l0;
        out[a*48 + 16 + k] = l1;
        out[a*48 + 32 + k] = l2;
    }
}

// ======================= launch =======================

extern "C" void kernel_launch(void* const* d_in, const int* in_sizes, int n_in,
                              void* d_out, int out_size, void* d_ws, size_t ws_size,
                              hipStream_t stream) {
    const float* cart   = (const float*)d_in[0];
    const float* rs     = (const float*)d_in[1];
    const float* inta   = (const float*)d_in[2];
    const float* params = (const float*)d_in[3];
    const int* atom_index    = (const int*)d_in[4];
    const int* neigh_species = (const int*)d_in[6];
    int nlocal = in_sizes[5];
    int nneigh = in_sizes[6];
    const int* idx0 = atom_index;
    const int* idx1 = atom_index + nneigh;

    int tb = 256;
    int nblkN = (nneigh + tb - 1) / tb;
    int nc = (nneigh + CHUNK - 1) >> LOG2CHUNK;
    int halfp = (((nlocal + 1) >> 1) + 63) & ~63;   // padded bins per parity
    int nlocalp = (nlocal + 63) & ~63;              // padded atoms (chunkpreT rows)
    int nblkB = (nlocal + 1023) / 1024;             // 1024-atom scan blocks

    char* ws = (char*)d_ws;
    size_t off = 0;
    auto carve = [&](size_t bytes) -> char* {
        off = (off + 255) & ~(size_t)255;
        char* p = ws + off; off += bytes; return p;
    };
    unsigned* counts        = (unsigned*)carve((size_t)nlocal * 4);
    unsigned* offsets       = (unsigned*)carve(((size_t)nlocal + 1) * 4);
    unsigned* cursor        = (unsigned*)carve((size_t)nlocal * 4);
    unsigned* partials      = (unsigned*)carve(256 * 4);
    uint4*    srec          = (uint4*)carve((size_t)nneigh * 16);
    unsigned short* lrank   = (unsigned short*)carve((size_t)nneigh * 2);
    unsigned short* hist16  = (unsigned short*)carve((size_t)nc * 2 * halfp * 2);
    unsigned short* chunkpreT = (unsigned short*)carve((size_t)nc * nlocalp * 2);
    size_t need_fast = off;

    bool fast = (ws_size >= need_fast) && (nblkB <= 64) &&
                (halfp <= 2 * HIST_WORDS) && (nc <= 64);

    if (fast) {
        chunk_hist_rank<<<nc * 2, 1024, 0, stream>>>(idx0, lrank, hist16, nneigh, halfp);
        count_partial<<<nblkB, 1024, 0, stream>>>(hist16, partials, nlocal, nc, halfp);
        scan_offsets_chunkpre<<<nblkB, 1024, 0, stream>>>(hist16, partials, offsets,
                                                          chunkpreT, nlocal, nblkB, nc,
                                                          halfp, nlocalp);
        geom_scatter_direct<<<nblkN, tb, 0, stream>>>(cart, idx0, idx1, neigh_species,
                                                      lrank, offsets, chunkpreT, srec,
                                                      nneigh, nlocalp);
        density_seq<<<(nlocal + 3) / 4, 256, 0, stream>>>(rs, inta, params, offsets, srec,
                                                          (float*)d_out, nlocal, nneigh);
    } else {
        unsigned* sorted = (unsigned*)srec;   // reuse region
        hipMemsetAsync(counts, 0, (size_t)nlocal * 4, stream);
        hist_kernel<<<nblkN, tb, 0, stream>>>(idx0, counts, nneigh);
        scan_kernel_1blk<<<1, 1024, 0, stream>>>(counts, offsets, cursor, nlocal);
        scatter_idx<<<nblkN, tb, 0, stream>>>(idx0, cursor, sorted, nneigh);
        density_kernel<<<(nlocal + 3) / 4, 256, 0, stream>>>(cart, rs, inta, params, idx1,
                                                             neigh_species, offsets, sorted,
                                                             (float*)d_out, nlocal);
    }
}